// Round 9
// baseline (104.936 us; speedup 1.0000x reference)
//
#include <hip/hip_runtime.h>

#define BATCH 8192
#define IN_DIM 512
#define NT 64
#define NI 31
#define NL 32
#define ODIM 16
#define NPAD (NT*NL)   // 2048 padded GEMM columns
#define NCB 16         // column blocks (2048/128)

typedef __attribute__((ext_vector_type(8))) short bf16x8;
typedef __attribute__((ext_vector_type(4))) float f32x4;

__device__ __forceinline__ unsigned short f2b(float f) {
  union { float f; unsigned int u; } v; v.f = f;
  unsigned int r = v.u + 0x7fffu + ((v.u >> 16) & 1u);   // RNE
  return (unsigned short)(r >> 16);
}
__device__ __forceinline__ float b2f(unsigned short h) {
  union { unsigned int u; float f; } v; v.u = ((unsigned int)h) << 16;
  return v.f;
}

// ---------------------------------------------------------------------------
// prep: x,W fp32 -> bf16 with 16B-granule XOR swizzle (slot g of each 32-K
// window holds source granule g ^ ((row>>1)&3)) so the GEMM's LDS reads are
// bank-conflict-free; W padded to 32 cols/tree; leaf softmax * (1/NT).
// ---------------------------------------------------------------------------
__global__ __launch_bounds__(256) void prep_kernel(
    const float* __restrict__ x, const float* __restrict__ W,
    const float* __restrict__ leafs,
    unsigned short* __restrict__ xb, unsigned short* __restrict__ wb,
    float* __restrict__ lsm)
{
  const int NXg = BATCH * (IN_DIM/8);   // 524288 granules of 8
  const int NWg = NPAD  * (IN_DIM/8);   // 131072 granules
  const int NS  = NT*NL;                // 2048 leaf rows
  int gid = blockIdx.x*256 + threadIdx.x;
  if (gid < NXg) {
    int row = gid >> 6, k8 = gid & 63;
    int kt = k8 >> 2, g = k8 & 3;
    int gs = g ^ ((row >> 1) & 3);
    const float* s = x + (size_t)row*IN_DIM + kt*32 + gs*8;
    float4 v0 = ((const float4*)s)[0], v1 = ((const float4*)s)[1];
    ushort4 o0, o1;
    o0.x=f2b(v0.x); o0.y=f2b(v0.y); o0.z=f2b(v0.z); o0.w=f2b(v0.w);
    o1.x=f2b(v1.x); o1.y=f2b(v1.y); o1.z=f2b(v1.z); o1.w=f2b(v1.w);
    ((ushort4*)xb)[gid*2]   = o0;
    ((ushort4*)xb)[gid*2+1] = o1;
  } else if ((gid -= NXg) < NWg) {
    int row = gid >> 6, k8 = gid & 63;
    int t = row >> 5, i = row & 31;
    int kt = k8 >> 2, g = k8 & 3;
    int gs = g ^ ((row >> 1) & 3);
    ushort4 o0, o1;
    if (i == 31) { o0.x=o0.y=o0.z=o0.w=0; o1=o0; }
    else {
      const float* s = W + (size_t)(t*NI+i)*IN_DIM + kt*32 + gs*8;
      float4 v0 = ((const float4*)s)[0], v1 = ((const float4*)s)[1];
      o0.x=f2b(v0.x); o0.y=f2b(v0.y); o0.z=f2b(v0.z); o0.w=f2b(v0.w);
      o1.x=f2b(v1.x); o1.y=f2b(v1.y); o1.z=f2b(v1.z); o1.w=f2b(v1.w);
    }
    ((ushort4*)wb)[gid*2]   = o0;
    ((ushort4*)wb)[gid*2+1] = o1;
  } else if ((gid -= NWg) < NS) {
    const float* src = leafs + (size_t)gid*ODIM;
    float m = src[0];
    #pragma unroll
    for (int o=1;o<ODIM;++o) m = fmaxf(m, src[o]);
    float e[ODIM]; float s = 0.f;
    #pragma unroll
    for (int o=0;o<ODIM;++o) { e[o] = __expf(src[o]-m); s += e[o]; }
    float inv = 1.f/(s*(float)NT);
    #pragma unroll
    for (int o=0;o<ODIM;++o) lsm[(size_t)gid*ODIM+o] = e[o]*inv;
  }
}

// ---------------------------------------------------------------------------
// fused: bf16 GEMM (M=8192,N=2048,K=512) tile 128x128 + sigmoid + route
// expansion + second MFMA (routes[128x128] @ lsm_slice[128x16]).
// 4 waves (2x2 of 64x64), 2-stage dbuf staging (32 KB), LDS max 34.8 KB ->
// 4 blocks/CU = 4 waves/SIMD (the occupancy this round buys).
// Epilogue overlay: Pt[128][130] bf16 then Rt[128][136] bf16.
// ---------------------------------------------------------------------------
__device__ __forceinline__ void async16(const unsigned short* g, unsigned short* l) {
  __builtin_amdgcn_global_load_lds(
      (const __attribute__((address_space(1))) unsigned int*)g,
      (__attribute__((address_space(3))) unsigned int*)l,
      16, 0, 0);
}

#define STG 8192          // shorts per stage: A 128*32=4096 + B 128*32=4096

__global__ __launch_bounds__(256, 4) void fused_kernel(
    const unsigned short* __restrict__ xb, const unsigned short* __restrict__ wb,
    const float* __restrict__ bias, const float* __restrict__ lsm,
    float* __restrict__ part)
{
  // max(staging 2*8192, Pt 128*130=16640, Rt 128*136=17408) shorts
  __shared__ __align__(16) unsigned short smem[17408];   // 34816 B

  const int tid  = threadIdx.x;
  const int lane = tid & 63;
  const int wave = tid >> 6;
  const int wm = wave & 1, wn = wave >> 1;   // wave-tile: 64x64

  // XCD-aware block swizzle: xcd = bid&7 covers 8 m-strips x all n
  const int bid  = blockIdx.x;
  const int loc  = bid >> 3;                 // 0..127
  const int n_t  = loc & 15;                 // 0..15
  const int m_t  = (bid & 7)*8 + (loc >> 4); // 0..63
  const int m0 = m_t * 128, n0 = n_t * 128;

  f32x4 acc[4][4];
  #pragma unroll
  for (int i=0;i<4;++i)
    #pragma unroll
    for (int j=0;j<4;++j) { f32x4 z = {0.f,0.f,0.f,0.f}; acc[i][j] = z; }

  const int srow = lane >> 2, scol = (lane & 3) * 8;
  const int qa = wave*2;
  const unsigned short* ga0 = xb + (size_t)(m0 + qa*16 + srow)*IN_DIM + scol;
  const unsigned short* gb0 = wb + (size_t)(n0 + qa*16 + srow)*IN_DIM + scol;

  const int l15 = lane & 15, quad = lane >> 4;
  const int cs   = (quad ^ ((l15 >> 1) & 3)) << 3;   // swizzled K-granule offset

  // prologue: tile 0 into stage 0
  async16(ga0,             smem + qa*512);
  async16(ga0 + 16*IN_DIM, smem + qa*512 + 512);
  async16(gb0,             smem + 4096 + qa*512);
  async16(gb0 + 16*IN_DIM, smem + 4096 + qa*512 + 512);

  for (int kt = 0; kt < 16; ++kt) {
    __syncthreads();                       // drains tile-kt loads + prior reads
    const int cur = (kt & 1) * STG;
    if (kt < 15) {                         // prefetch kt+1 into other stage
      const int nxt = ((kt + 1) & 1) * STG;
      const int ko = (kt + 1) * 32;
      async16(ga0 + ko,             smem + nxt + qa*512);
      async16(ga0 + ko + 16*IN_DIM, smem + nxt + qa*512 + 512);
      async16(gb0 + ko,             smem + nxt + 4096 + qa*512);
      async16(gb0 + ko + 16*IN_DIM, smem + nxt + 4096 + qa*512 + 512);
    }
    const unsigned short* As = smem + cur;
    const unsigned short* Bs = smem + cur + 4096;
    bf16x8 af[4], bfr[4];
    #pragma unroll
    for (int mi=0;mi<4;++mi)
      af[mi] = *(const bf16x8*)(As + (wm*64 + mi*16 + l15)*32 + cs);
    #pragma unroll
    for (int ni=0;ni<4;++ni)
      bfr[ni] = *(const bf16x8*)(Bs + (wn*64 + ni*16 + l15)*32 + cs);
    #pragma unroll
    for (int mi=0;mi<4;++mi)
      #pragma unroll
      for (int ni=0;ni<4;++ni)
        acc[mi][ni] = __builtin_amdgcn_mfma_f32_16x16x32_bf16(
            af[mi], bfr[ni], acc[mi][ni], 0, 0, 0);
  }

  // lsm B-frags for the second MFMA: lane(l15=n, quad) elem j = bf16 of
  // lsm[(t0+s)*32 + quad*8 + j][l15]
  bf16x8 bleaf[4];
  {
    const int t0 = n_t * 4;
    #pragma unroll
    for (int s=0;s<4;++s) {
      union { bf16x8 v; unsigned short u[8]; } tmp;
      #pragma unroll
      for (int j=0;j<8;++j)
        tmp.u[j] = f2b(lsm[((size_t)(t0+s)*NL + quad*8 + j)*ODIM + l15]);
      bleaf[s] = tmp.v;
    }
  }

  __syncthreads();   // staging ds_reads done before Pt overlays staging

  // Phase A: bias + sigmoid -> Pt[128][130] bf16
  unsigned short* Pt = smem;
  #pragma unroll
  for (int ni=0;ni<4;++ni) {
    int cl = wn*64 + ni*16 + l15;          // local col 0..127
    int gcol = n0 + cl;
    int tt = gcol >> 5, ii = gcol & 31;
    float bv = (ii < NI) ? bias[tt*NI + ii] : 0.f;
    #pragma unroll
    for (int mi=0;mi<4;++mi) {
      int lrow = wm*64 + mi*16 + quad*4;
      #pragma unroll
      for (int r=0;r<4;++r) {
        float v = acc[mi][ni][r] + bv;
        Pt[(lrow + r)*130 + cl] = f2b(1.f/(1.f + __expf(-v)));
      }
    }
  }
  __syncthreads();

  // Phase B: thread pair (row = tid>>1) expands 2 trees each into bf16 route
  // pairs; streamed per tree to keep VGPR pressure low (no spill at (256,4)).
  const int row  = tid >> 1;
  const int half = tid & 1;
  unsigned int rt[32];
  #pragma unroll
  for (int sel=0; sel<2; ++sel) {
    const int tl = half*2 + sel;
    const unsigned short* pr = Pt + row*130 + tl*32;
    float v[32];
    float p0 = b2f(pr[0]);
    v[0] = p0; v[1] = 1.f - p0;
    #pragma unroll
    for (int d=1; d<=4; ++d) {
      const int s = 1 << d;
      #pragma unroll
      for (int j=s-1; j>=0; --j) {
        float pj = b2f(pr[(s-1)+j]);
        float base = v[j];
        v[2*j]   = base * pj;
        v[2*j+1] = base * (1.f - pj);
      }
    }
    #pragma unroll
    for (int k=0;k<16;++k)
      rt[sel*16+k] = (unsigned int)f2b(v[2*k]) | ((unsigned int)f2b(v[2*k+1]) << 16);
  }
  __syncthreads();   // all Pt reads done before Rt overwrites

  // Rt[128][136] bf16 rows (272 B, 16B-aligned); thread writes its 2 trees
  unsigned int* Rt32 = (unsigned int*)smem;
  {
    uint4* dst = (uint4*)(Rt32 + row*68 + half*32);
    #pragma unroll
    for (int c=0;c<8;++c) {
      uint4 w; w.x=rt[c*4]; w.y=rt[c*4+1]; w.z=rt[c*4+2]; w.w=rt[c*4+3];
      dst[c] = w;
    }
  }
  __syncthreads();

  // second MFMA: routes[128x128] @ lsm[128x16]; wave covers mtiles 2w..2w+1
  const unsigned short* RtS = smem;
  #pragma unroll
  for (int mt=0; mt<2; ++mt) {
    const int mrow = (wave*2 + mt)*16;
    f32x4 a2 = {0.f,0.f,0.f,0.f};
    #pragma unroll
    for (int s=0;s<4;++s) {
      bf16x8 af2 = *(const bf16x8*)(RtS + (mrow + l15)*136 + s*32 + quad*8);
      a2 = __builtin_amdgcn_mfma_f32_16x16x32_bf16(af2, bleaf[s], a2, 0, 0, 0);
    }
    // C/D: col=l15 (ODIM), row=quad*4+r
    float* op = part + ((size_t)n_t*BATCH + (m0 + mrow + quad*4))*ODIM + l15;
    #pragma unroll
    for (int r=0;r<4;++r)
      op[r*ODIM] = a2[r];
  }
}

// ---------------------------------------------------------------------------
// reduce: out[row][o] = sum over 16 colblock partials
// ---------------------------------------------------------------------------
__global__ __launch_bounds__(256) void reduce_kernel(
    const float* __restrict__ part, float* __restrict__ out)
{
  int gid = blockIdx.x*256 + threadIdx.x;   // 32768 float4 tasks
  const float4* p4 = (const float4*)part;
  float4 s = p4[gid];
  #pragma unroll
  for (int cb=1; cb<NCB; ++cb) {
    float4 v = p4[(size_t)cb*(BATCH*ODIM/4) + gid];
    s.x+=v.x; s.y+=v.y; s.z+=v.z; s.w+=v.w;
  }
  ((float4*)out)[gid] = s;
}

// ---------------------------------------------------------------------------
extern "C" void kernel_launch(void* const* d_in, const int* in_sizes, int n_in,
                              void* d_out, int out_size, void* d_ws, size_t ws_size,
                              hipStream_t stream) {
  const float* x     = (const float*)d_in[0];
  const float* W     = (const float*)d_in[1];
  const float* b     = (const float*)d_in[2];
  const float* leafs = (const float*)d_in[3];
  float* out = (float*)d_out;

  char* ws = (char*)d_ws;
  unsigned short* xb  = (unsigned short*)ws;                       // 8,388,608 B
  unsigned short* wb  = (unsigned short*)(ws + 8388608);           // 2,097,152 B
  float*          lsm = (float*)(ws + 10485760);                   //   131,072 B
  float*          part= (float*)(ws + 10616832);                   // 8,388,608 B

  const int total = BATCH*(IN_DIM/8) + NPAD*(IN_DIM/8) + NT*NL;    // 657408
  prep_kernel<<<dim3((total + 255)/256), dim3(256), 0, stream>>>(
      x, W, leafs, xb, wb, lsm);
  fused_kernel<<<dim3(1024), dim3(256), 0, stream>>>(
      xb, wb, b, lsm, part);
  reduce_kernel<<<dim3(BATCH*ODIM/4/256), dim3(256), 0, stream>>>(part, out);
}